// Round 1
// baseline (271.226 us; speedup 1.0000x reference)
//
#include <hip/hip_runtime.h>
#include <hip/hip_bf16.h>
#include <math.h>

#define NB 4
#define NL 2048
#define NH 8
#define NE 64
#define ND 64
#define EPSF 1e-6f
#define LOG2E 1.44269504088896340736f

typedef __attribute__((ext_vector_type(8))) short bf16x8;
typedef __attribute__((ext_vector_type(4))) float f32x4;

// ---------------- kernel 1: k_sum / q_sum over L (atomic accumulate) ------------
__global__ void sums_kernel(const float* __restrict__ q, const float* __restrict__ k,
                            float* __restrict__ qsum, float* __restrict__ ksum) {
  int bh = blockIdx.x;           // 0..31
  int lp = blockIdx.y;           // 0..7  (L sliced into 8 chunks of 256)
  int e = threadIdx.x & 63, sub = threadIdx.x >> 6;
  int b = bh >> 3, h = bh & 7;
  size_t base = (((size_t)b * NL) * NH + h) * NE + e;
  const float* qp = q + base;
  const float* kp = k + base;
  float sq = 0.f, sk = 0.f;
  for (int i = 0; i < 64; ++i) {
    int l = lp * 256 + i * 4 + sub;
    size_t off = (size_t)l * NH * NE;
    sq += qp[off];
    sk += kp[off];
  }
  __shared__ float s1[256], s2[256];
  s1[threadIdx.x] = sq; s2[threadIdx.x] = sk;
  __syncthreads();
  if (sub == 0) {
    sq = s1[e] + s1[e + 64] + s1[e + 128] + s1[e + 192];
    sk = s2[e] + s2[e + 64] + s2[e + 128] + s2[e + 192];
    atomicAdd(&qsum[bh * NE + e], sq);
    atomicAdd(&ksum[bh * NE + e], sk);
  }
}

// ---------------- kernel 2: adjust (sign-sqrt + L2 normalize) -> bf16 [B,H,L,E] --
__global__ void adjust_kernel(const float* __restrict__ q, const float* __restrict__ k,
                              const float* __restrict__ qsum, const float* __restrict__ ksum,
                              const float* __restrict__ alpha,
                              __hip_bfloat16* __restrict__ qadj, __hip_bfloat16* __restrict__ kadj) {
  int wid = (int)((blockIdx.x * 256 + threadIdx.x) >> 6);  // row id over B*L*H
  int lane = threadIdx.x & 63;
  int h = wid & 7;
  int l = (wid >> 3) & (NL - 1);
  int b = wid >> 14;
  float al = alpha[0];
  size_t ioff = (((size_t)b * NL + l) * NH + h) * NE + lane;
  int bh = b * NH + h;
  float xq = q[ioff] + al * ksum[bh * NE + lane];
  float xk = k[ioff] + al * qsum[bh * NE + lane];
  float yq = (xq > 0.f) ? sqrtf(xq + EPSF) : ((xq < 0.f) ? -sqrtf(-xq + EPSF) : 0.f);
  float yk = (xk > 0.f) ? sqrtf(xk + EPSF) : ((xk < 0.f) ? -sqrtf(-xk + EPSF) : 0.f);
  float nq = yq * yq, nk = yk * yk;
#pragma unroll
  for (int m = 1; m < 64; m <<= 1) {
    nq += __shfl_xor(nq, m, 64);
    nk += __shfl_xor(nk, m, 64);
  }
  float rq = yq / (sqrtf(nq) + EPSF);
  float rk = yk / (sqrtf(nk) + EPSF);
  size_t ooff = ((size_t)bh * NL + l) * NE + lane;
  qadj[ooff] = __float2bfloat16(rq);
  kadj[ooff] = __float2bfloat16(rk);
}

// ---------------- kernel 3: V [B,S,H,D] f32 -> VT [B,H,D,S] bf16 ----------------
__global__ void vtrans_kernel(const float* __restrict__ v, __hip_bfloat16* __restrict__ vt) {
  __shared__ __hip_bfloat16 tile[64][68];  // +4 pad to break bank conflicts
  int s0 = blockIdx.x * 64;
  int bh = blockIdx.y;
  int b = bh >> 3, h = bh & 7;
  int t = threadIdx.x;
  {
    int sl = t >> 2, dg = t & 3;
    const float* src = v + (((size_t)b * NL + s0 + sl) * NH + h) * ND + dg * 16;
#pragma unroll
    for (int i = 0; i < 4; ++i) {
      float4 f = *(const float4*)(src + i * 4);
      tile[sl][dg * 16 + i * 4 + 0] = __float2bfloat16(f.x);
      tile[sl][dg * 16 + i * 4 + 1] = __float2bfloat16(f.y);
      tile[sl][dg * 16 + i * 4 + 2] = __float2bfloat16(f.z);
      tile[sl][dg * 16 + i * 4 + 3] = __float2bfloat16(f.w);
    }
  }
  __syncthreads();
  {
    int d = t >> 2, sg = t & 3;
    __align__(16) __hip_bfloat16 tmp[16];
#pragma unroll
    for (int i = 0; i < 16; ++i) tmp[i] = tile[sg * 16 + i][d];
    __hip_bfloat16* dst = vt + ((size_t)bh * ND + d) * NL + s0 + sg * 16;
    *(bf16x8*)(dst) = *(const bf16x8*)&tmp[0];
    *(bf16x8*)(dst + 8) = *(const bf16x8*)&tmp[8];
  }
}

// ---------------- kernel 4: causal flash attention, bf16 MFMA -------------------
// block: 256 thr = 4 waves, each wave owns 16 q rows; s-chunks of 64.
// LDS: K tile [64s][64e] bf16 (8KB, xor-swizzled), V tile [64d][64s] (8KB),
//      per-wave P tile [16q][64s] (2KB x4).
__global__ __launch_bounds__(256) void attn_kernel(const __hip_bfloat16* __restrict__ qadj,
                                                   const __hip_bfloat16* __restrict__ kadj,
                                                   const __hip_bfloat16* __restrict__ vt,
                                                   float* __restrict__ out) {
  __shared__ __align__(16) char lds[24576];
  char* ldsK = lds;
  char* ldsV = lds + 8192;
  int qb = blockIdx.x, bh = blockIdx.y;
  int b = bh >> 3, h = bh & 7;
  int wave = threadIdx.x >> 6, lane = threadIdx.x & 63;
  char* ldsP = lds + 16384 + wave * 2048;
  int qr = lane & 15, eg = lane >> 4;
  int q0 = qb * 64;
  const char* kgb = (const char*)(kadj + (size_t)bh * NL * NE);
  const char* vgb = (const char*)(vt + (size_t)bh * ND * NL);
  const char* qgb = (const char*)(qadj + (size_t)bh * NL * NE);

  // Q A-fragments direct from global: lane supplies Q[qr][ch*32 + eg*8 + j]
  bf16x8 qf[2];
#pragma unroll
  for (int ch = 0; ch < 2; ++ch)
    qf[ch] = *(const bf16x8*)(qgb + ((size_t)(q0 + wave * 16 + qr) * NE + ch * 32 + eg * 8) * 2);

  f32x4 acc[4];
  float mrun[4], srun[4];
#pragma unroll
  for (int dc = 0; dc < 4; ++dc) acc[dc] = (f32x4){0.f, 0.f, 0.f, 0.f};
#pragma unroll
  for (int vv = 0; vv < 4; ++vv) { mrun[vv] = -1e30f; srun[vv] = 0.f; }

  for (int ck = 0; ck <= qb; ++ck) {
    int s0 = ck * 64;
    // stage K tile: global rows contiguous; inverse-swizzle the SOURCE (linear LDS dest)
#pragma unroll
    for (int c = 0; c < 2; ++c) {
      int T = wave * 2048 + c * 1024 + lane * 16;
      int S = T ^ (((T >> 7) & 7) << 4);
      __builtin_amdgcn_global_load_lds(
          (const __attribute__((address_space(1))) unsigned int*)(kgb + (size_t)s0 * 128 + S),
          (__attribute__((address_space(3))) unsigned int*)(ldsK + wave * 2048 + c * 1024),
          16, 0, 0);
    }
    // stage V tile rows d (global stride NL*2), cols [s0, s0+64)
#pragma unroll
    for (int c = 0; c < 2; ++c) {
      int T = wave * 2048 + c * 1024 + lane * 16;
      int S = T ^ (((T >> 7) & 7) << 4);
      int d = S >> 7, cc = S & 127;
      __builtin_amdgcn_global_load_lds(
          (const __attribute__((address_space(1))) unsigned int*)(vgb + ((size_t)d * NL + s0) * 2 + cc),
          (__attribute__((address_space(3))) unsigned int*)(ldsV + wave * 2048 + c * 1024),
          16, 0, 0);
    }
    __syncthreads();

    // ---- QK^T: 4 s-subtiles x (2 e-chunks) ----
    float lg[4][4];
#pragma unroll
    for (int st = 0; st < 4; ++st) {
      f32x4 a = (f32x4){0.f, 0.f, 0.f, 0.f};
      int row = st * 16 + qr;
      int swz = (row & 7) << 4;
      bf16x8 k0 = *(const bf16x8*)(ldsK + ((row * 128 + eg * 16) ^ swz));
      bf16x8 k1 = *(const bf16x8*)(ldsK + ((row * 128 + 64 + eg * 16) ^ swz));
      a = __builtin_amdgcn_mfma_f32_16x16x32_bf16(qf[0], k0, a, 0, 0, 0);
      a = __builtin_amdgcn_mfma_f32_16x16x32_bf16(qf[1], k1, a, 0, 0, 0);
#pragma unroll
      for (int vv = 0; vv < 4; ++vv) lg[st][vv] = a[vv] * 0.125f;
    }
    // causal mask: only the diagonal chunk needs it (s0 == q0 there)
    if (ck == qb) {
#pragma unroll
      for (int st = 0; st < 4; ++st)
#pragma unroll
        for (int vv = 0; vv < 4; ++vv)
          if (st * 16 + qr > wave * 16 + eg * 4 + vv) lg[st][vv] = -1e30f;
    }

    // ---- online softmax over this 64-s chunk (row state per 16-lane group) ----
#pragma unroll
    for (int vv = 0; vv < 4; ++vv) {
      float tm = fmaxf(fmaxf(lg[0][vv], lg[1][vv]), fmaxf(lg[2][vv], lg[3][vv]));
#pragma unroll
      for (int m = 1; m < 16; m <<= 1) tm = fmaxf(tm, __shfl_xor(tm, m, 16));
      float mnew = fmaxf(mrun[vv], tm);
      float fac = exp2f((mrun[vv] - mnew) * LOG2E);
      mrun[vv] = mnew;
      float ts = 0.f;
#pragma unroll
      for (int st = 0; st < 4; ++st) {
        lg[st][vv] = exp2f((lg[st][vv] - mnew) * LOG2E);
        ts += lg[st][vv];
      }
#pragma unroll
      for (int m = 1; m < 16; m <<= 1) ts += __shfl_xor(ts, m, 16);
      srun[vv] = srun[vv] * fac + ts;
#pragma unroll
      for (int dc = 0; dc < 4; ++dc) acc[dc][vv] *= fac;
    }

    // ---- P -> per-wave LDS (D-layout scatter), then read back as A-fragments ----
#pragma unroll
    for (int st = 0; st < 4; ++st)
#pragma unroll
      for (int vv = 0; vv < 4; ++vv) {
        int qrow = eg * 4 + vv, scol = st * 16 + qr;
        int byt = (qrow * 128 + scol * 2) ^ ((qrow & 7) << 4);
        *(__hip_bfloat16*)(ldsP + byt) = __float2bfloat16(lg[st][vv]);
      }
    asm volatile("s_waitcnt lgkmcnt(0)" ::: "memory");

    // ---- PV: 2 s-halves x 4 d-chunks ----
#pragma unroll
    for (int hh = 0; hh < 2; ++hh) {
      int pswz = (qr & 7) << 4;
      bf16x8 pa = *(const bf16x8*)(ldsP + ((qr * 128 + hh * 64 + eg * 16) ^ pswz));
#pragma unroll
      for (int dc = 0; dc < 4; ++dc) {
        int d = dc * 16 + qr;
        bf16x8 vf = *(const bf16x8*)(ldsV + ((d * 128 + hh * 64 + eg * 16) ^ ((d & 7) << 4)));
        acc[dc] = __builtin_amdgcn_mfma_f32_16x16x32_bf16(pa, vf, acc[dc], 0, 0, 0);
      }
    }
    __syncthreads();
  }

  // ---- epilogue: divide by softmax denominator, write [B,L,H,D] f32 ----
#pragma unroll
  for (int vv = 0; vv < 4; ++vv) {
    float inv = 1.f / srun[vv];
    int l = q0 + wave * 16 + eg * 4 + vv;
    float* orow = out + (((size_t)b * NL + l) * NH + h) * ND;
#pragma unroll
    for (int dc = 0; dc < 4; ++dc) orow[dc * 16 + qr] = acc[dc][vv] * inv;
  }
}

extern "C" void kernel_launch(void* const* d_in, const int* in_sizes, int n_in,
                              void* d_out, int out_size, void* d_ws, size_t ws_size,
                              hipStream_t stream) {
  const float* q = (const float*)d_in[0];
  const float* k = (const float*)d_in[1];
  const float* v = (const float*)d_in[2];
  // d_in[3] = attn_mask: deterministic triu(k=1) causal mask — applied analytically
  const float* alpha = (const float*)d_in[4];
  float* out = (float*)d_out;
  char* ws = (char*)d_ws;

  __hip_bfloat16* qadj = (__hip_bfloat16*)(ws);                 // 8 MiB  [B,H,L,E]
  __hip_bfloat16* kadj = (__hip_bfloat16*)(ws + 8388608);       // 8 MiB  [B,H,L,E]
  __hip_bfloat16* vt   = (__hip_bfloat16*)(ws + 16777216);      // 8 MiB  [B,H,D,S]
  float* qsum = (float*)(ws + 25165824);                        // 8 KiB
  float* ksum = (float*)(ws + 25165824 + 8192);                 // 8 KiB

  hipMemsetAsync(ws + 25165824, 0, 16384, stream);
  sums_kernel<<<dim3(32, 8), 256, 0, stream>>>(q, k, qsum, ksum);
  adjust_kernel<<<dim3(16384), 256, 0, stream>>>(q, k, qsum, ksum, alpha, qadj, kadj);
  vtrans_kernel<<<dim3(32, 32), 256, 0, stream>>>(v, vt);
  attn_kernel<<<dim3(32, 32), 256, 0, stream>>>(qadj, kadj, vt, out);
}

// Round 2
// 174.740 us; speedup vs baseline: 1.5522x; 1.5522x over previous
//
#include <hip/hip_runtime.h>
#include <hip/hip_bf16.h>
#include <math.h>

#define NB 4
#define NL 2048
#define NH 8
#define NE 64
#define ND 64
#define EPSF 1e-6f
#define CEXP 0.180336881f  // 0.125 * log2(e): scores are L2-norm-bounded, fixed max = 1.0

typedef __attribute__((ext_vector_type(8))) short bf16x8;
typedef __attribute__((ext_vector_type(4))) float f32x4;

// ---------------- kernel 1: k_sum / q_sum over L (atomic accumulate) ------------
__global__ void sums_kernel(const float* __restrict__ q, const float* __restrict__ k,
                            float* __restrict__ qsum, float* __restrict__ ksum) {
  int bh = blockIdx.x;           // 0..31
  int lp = blockIdx.y;           // 0..31 (L sliced into 32 chunks of 64)
  int e = threadIdx.x & 63, sub = threadIdx.x >> 6;
  int b = bh >> 3, h = bh & 7;
  size_t base = (((size_t)b * NL) * NH + h) * NE + e;
  const float* qp = q + base;
  const float* kp = k + base;
  float sq = 0.f, sk = 0.f;
#pragma unroll
  for (int i = 0; i < 16; ++i) {
    int l = lp * 64 + i * 4 + sub;
    size_t off = (size_t)l * NH * NE;
    sq += qp[off];
    sk += kp[off];
  }
  __shared__ float s1[256], s2[256];
  s1[threadIdx.x] = sq; s2[threadIdx.x] = sk;
  __syncthreads();
  if (sub == 0) {
    sq = s1[e] + s1[e + 64] + s1[e + 128] + s1[e + 192];
    sk = s2[e] + s2[e + 64] + s2[e + 128] + s2[e + 192];
    atomicAdd(&qsum[bh * NE + e], sq);
    atomicAdd(&ksum[bh * NE + e], sk);
  }
}

// ---------------- kernel 2: adjust (sign-sqrt + L2 normalize) -> bf16 [B,H,L,E] --
__global__ void adjust_kernel(const float* __restrict__ q, const float* __restrict__ k,
                              const float* __restrict__ qsum, const float* __restrict__ ksum,
                              const float* __restrict__ alpha,
                              __hip_bfloat16* __restrict__ qadj, __hip_bfloat16* __restrict__ kadj) {
  int wid = (int)((blockIdx.x * 256 + threadIdx.x) >> 6);  // row id over B*L*H
  int lane = threadIdx.x & 63;
  int h = wid & 7;
  int l = (wid >> 3) & (NL - 1);
  int b = wid >> 14;
  float al = alpha[0];
  size_t ioff = (((size_t)b * NL + l) * NH + h) * NE + lane;
  int bh = b * NH + h;
  float xq = q[ioff] + al * ksum[bh * NE + lane];
  float xk = k[ioff] + al * qsum[bh * NE + lane];
  float yq = (xq > 0.f) ? sqrtf(xq + EPSF) : ((xq < 0.f) ? -sqrtf(-xq + EPSF) : 0.f);
  float yk = (xk > 0.f) ? sqrtf(xk + EPSF) : ((xk < 0.f) ? -sqrtf(-xk + EPSF) : 0.f);
  float nq = yq * yq, nk = yk * yk;
#pragma unroll
  for (int m = 1; m < 64; m <<= 1) {
    nq += __shfl_xor(nq, m, 64);
    nk += __shfl_xor(nk, m, 64);
  }
  float rq = yq / (sqrtf(nq) + EPSF);
  float rk = yk / (sqrtf(nk) + EPSF);
  size_t ooff = ((size_t)bh * NL + l) * NE + lane;
  qadj[ooff] = __float2bfloat16(rq);
  kadj[ooff] = __float2bfloat16(rk);
}

// ---------------- kernel 3: V [B,S,H,D] f32 -> VT [B,H,D,S] bf16 ----------------
__global__ void vtrans_kernel(const float* __restrict__ v, __hip_bfloat16* __restrict__ vt) {
  __shared__ __hip_bfloat16 tile[64][68];
  int s0 = blockIdx.x * 64;
  int bh = blockIdx.y;
  int b = bh >> 3, h = bh & 7;
  int t = threadIdx.x;
  {
    int sl = t >> 2, dg = t & 3;
    const float* src = v + (((size_t)b * NL + s0 + sl) * NH + h) * ND + dg * 16;
#pragma unroll
    for (int i = 0; i < 4; ++i) {
      float4 f = *(const float4*)(src + i * 4);
      tile[sl][dg * 16 + i * 4 + 0] = __float2bfloat16(f.x);
      tile[sl][dg * 16 + i * 4 + 1] = __float2bfloat16(f.y);
      tile[sl][dg * 16 + i * 4 + 2] = __float2bfloat16(f.z);
      tile[sl][dg * 16 + i * 4 + 3] = __float2bfloat16(f.w);
    }
  }
  __syncthreads();
  {
    int d = t >> 2, sg = t & 3;
    __align__(16) __hip_bfloat16 tmp[16];
#pragma unroll
    for (int i = 0; i < 16; ++i) tmp[i] = tile[sg * 16 + i][d];
    __hip_bfloat16* dst = vt + ((size_t)bh * ND + d) * NL + s0 + sg * 16;
    *(bf16x8*)(dst) = *(const bf16x8*)&tmp[0];
    *(bf16x8*)(dst + 8) = *(const bf16x8*)&tmp[8];
  }
}

// ---------------- kernel 4: causal flash attention, bf16 MFMA -------------------
// 512 thr = 8 waves, 128 q rows/block (16 per wave). Paired q-tiles (i, 15-i)
// for uniform cost (34 chunk-steps). Double-buffered K/V, 2-phase pipeline.
// LDS: 2 x (K 8KB + V 8KB) + 8 x 2KB P = 48KB.
__global__ __launch_bounds__(512) void attn_kernel(const __hip_bfloat16* __restrict__ qadj,
                                                   const __hip_bfloat16* __restrict__ kadj,
                                                   const __hip_bfloat16* __restrict__ vt,
                                                   float* __restrict__ out) {
  __shared__ __align__(16) char lds[49152];
  int bh = blockIdx.x;        // bh fastest => same-bh blocks land on same XCD
  int pairid = blockIdx.y;    // 0..7
  int b = bh >> 3, h = bh & 7;
  int wave = threadIdx.x >> 6, lane = threadIdx.x & 63;
  int qr = lane & 15, eg = lane >> 4;
  char* ldsP = lds + 32768 + wave * 2048;
  const char* kgb = (const char*)(kadj + (size_t)bh * NL * NE);
  const char* vgb = (const char*)(vt + (size_t)bh * ND * NL);
  const char* qgb = (const char*)(qadj + (size_t)bh * NL * NE);

  // stage chunk [s0, s0+64) into buffer bufsel: K rows contiguous; V rows d strided.
  auto STAGE = [&](int bufsel, int s0) {
    char* dstbase = lds + bufsel * 16384;
    if (wave < 4) {
#pragma unroll
      for (int c = 0; c < 2; ++c) {
        int T = wave * 2048 + c * 1024 + lane * 16;
        int S = T ^ (((T >> 7) & 7) << 4);
        __builtin_amdgcn_global_load_lds(
            (const __attribute__((address_space(1))) unsigned int*)(kgb + (size_t)s0 * 128 + S),
            (__attribute__((address_space(3))) unsigned int*)(dstbase + wave * 2048 + c * 1024),
            16, 0, 0);
      }
    } else {
      int w = wave - 4;
#pragma unroll
      for (int c = 0; c < 2; ++c) {
        int T = w * 2048 + c * 1024 + lane * 16;
        int S = T ^ (((T >> 7) & 7) << 4);
        int d = S >> 7, cc = S & 127;
        __builtin_amdgcn_global_load_lds(
            (const __attribute__((address_space(1))) unsigned int*)(vgb + ((size_t)d * NL + s0) * 2 + cc),
            (__attribute__((address_space(3))) unsigned int*)(dstbase + 8192 + w * 2048 + c * 1024),
            16, 0, 0);
      }
    }
  };

#pragma unroll 1
  for (int half = 0; half < 2; ++half) {
    int tile = (half == 0) ? pairid : (15 - pairid);
    int t0 = tile * 128;
    int nck = (t0 >> 6) + 2;
    int qw0 = t0 + wave * 16;

    bf16x8 qf0 = *(const bf16x8*)(qgb + ((size_t)(qw0 + qr) * NE + eg * 8) * 2);
    bf16x8 qf1 = *(const bf16x8*)(qgb + ((size_t)(qw0 + qr) * NE + 32 + eg * 8) * 2);

    f32x4 acc[4];
    float srun[4];
#pragma unroll
    for (int dc = 0; dc < 4; ++dc) acc[dc] = (f32x4){0.f, 0.f, 0.f, 0.f};
#pragma unroll
    for (int vv = 0; vv < 4; ++vv) srun[vv] = 0.f;

    // prologue: stage chunk 0 into buf 0
    STAGE(0, 0);
    asm volatile("s_waitcnt vmcnt(0)" ::: "memory");
    __builtin_amdgcn_sched_barrier(0);
    __builtin_amdgcn_s_barrier();

    int cur = 0;
#pragma unroll 1
    for (int ck = 0; ck < nck; ++ck) {
      int s0 = ck * 64;
      if (ck + 1 < nck) STAGE(cur ^ 1, s0 + 64);  // prefetch flies under this chunk's compute
      char* ldsK = lds + cur * 16384;
      char* ldsV = ldsK + 8192;

      // ---- QK^T (raw scores, in [-1,1] by L2 normalization) ----
      float p[4][4];
#pragma unroll
      for (int st = 0; st < 4; ++st) {
        f32x4 a = (f32x4){0.f, 0.f, 0.f, 0.f};
        int row = st * 16 + qr;
        int swz = (row & 7) << 4;
        bf16x8 k0 = *(const bf16x8*)(ldsK + ((row * 128 + eg * 16) ^ swz));
        bf16x8 k1 = *(const bf16x8*)(ldsK + ((row * 128 + 64 + eg * 16) ^ swz));
        a = __builtin_amdgcn_mfma_f32_16x16x32_bf16(qf0, k0, a, 0, 0, 0);
        a = __builtin_amdgcn_mfma_f32_16x16x32_bf16(qf1, k1, a, 0, 0, 0);
#pragma unroll
        for (int vv = 0; vv < 4; ++vv) p[st][vv] = a[vv];
      }
      // causal mask (only chunks overlapping this wave's rows)
      if (s0 + 63 > qw0) {
#pragma unroll
        for (int st = 0; st < 4; ++st)
#pragma unroll
          for (int vv = 0; vv < 4; ++vv)
            if (s0 + st * 16 + qr > qw0 + eg * 4 + vv) p[st][vv] = -1e30f;
      }
      // ---- fixed-max softmax numerators; denominator deferred (per-lane partial) ----
#pragma unroll
      for (int st = 0; st < 4; ++st)
#pragma unroll
        for (int vv = 0; vv < 4; ++vv) p[st][vv] = exp2f((p[st][vv] - 1.0f) * CEXP);
#pragma unroll
      for (int vv = 0; vv < 4; ++vv)
        srun[vv] += (p[0][vv] + p[1][vv]) + (p[2][vv] + p[3][vv]);

      // ---- P -> per-wave LDS (D-layout scatter), read back as A-fragments ----
#pragma unroll
      for (int st = 0; st < 4; ++st)
#pragma unroll
        for (int vv = 0; vv < 4; ++vv) {
          int qrow = eg * 4 + vv, scol = st * 16 + qr;
          int byt = (qrow * 128 + scol * 2) ^ ((qrow & 7) << 4);
          *(__hip_bfloat16*)(ldsP + byt) = __float2bfloat16(p[st][vv]);
        }
      asm volatile("s_waitcnt lgkmcnt(0)" ::: "memory");
      __builtin_amdgcn_sched_barrier(0);

      // ---- PV ----
#pragma unroll
      for (int hh = 0; hh < 2; ++hh) {
        int pswz = (qr & 7) << 4;
        bf16x8 pa = *(const bf16x8*)(ldsP + ((qr * 128 + hh * 64 + eg * 16) ^ pswz));
#pragma unroll
        for (int dc = 0; dc < 4; ++dc) {
          int d = dc * 16 + qr;
          bf16x8 vf = *(const bf16x8*)(ldsV + ((d * 128 + hh * 64 + eg * 16) ^ ((d & 7) << 4)));
          acc[dc] = __builtin_amdgcn_mfma_f32_16x16x32_bf16(pa, vf, acc[dc], 0, 0, 0);
        }
      }

      asm volatile("s_waitcnt vmcnt(0)" ::: "memory");  // next chunk's stage landed
      __builtin_amdgcn_sched_barrier(0);
      __builtin_amdgcn_s_barrier();
      cur ^= 1;
    }

    // ---- epilogue: finish denominator (one 16-lane reduce), normalize, store ----
#pragma unroll
    for (int vv = 0; vv < 4; ++vv) {
      float s = srun[vv];
#pragma unroll
      for (int m = 1; m < 16; m <<= 1) s += __shfl_xor(s, m, 16);
      float inv = 1.f / s;
      int l = qw0 + eg * 4 + vv;
      float* orow = out + (((size_t)b * NL + l) * NH + h) * ND;
#pragma unroll
      for (int dc = 0; dc < 4; ++dc) orow[dc * 16 + qr] = acc[dc][vv] * inv;
    }
  }
}

extern "C" void kernel_launch(void* const* d_in, const int* in_sizes, int n_in,
                              void* d_out, int out_size, void* d_ws, size_t ws_size,
                              hipStream_t stream) {
  const float* q = (const float*)d_in[0];
  const float* k = (const float*)d_in[1];
  const float* v = (const float*)d_in[2];
  // d_in[3] = attn_mask: deterministic triu(k=1) causal mask — applied analytically
  const float* alpha = (const float*)d_in[4];
  float* out = (float*)d_out;
  char* ws = (char*)d_ws;

  __hip_bfloat16* qadj = (__hip_bfloat16*)(ws);                 // 8 MiB  [B,H,L,E]
  __hip_bfloat16* kadj = (__hip_bfloat16*)(ws + 8388608);       // 8 MiB  [B,H,L,E]
  __hip_bfloat16* vt   = (__hip_bfloat16*)(ws + 16777216);      // 8 MiB  [B,H,D,S]
  float* qsum = (float*)(ws + 25165824);                        // 8 KiB
  float* ksum = (float*)(ws + 25165824 + 8192);                 // 8 KiB

  hipMemsetAsync(ws + 25165824, 0, 16384, stream);
  sums_kernel<<<dim3(32, 32), 256, 0, stream>>>(q, k, qsum, ksum);
  adjust_kernel<<<dim3(16384), 256, 0, stream>>>(q, k, qsum, ksum, alpha, qadj, kadj);
  vtrans_kernel<<<dim3(32, 32), 256, 0, stream>>>(v, vt);
  attn_kernel<<<dim3(32, 8), 512, 0, stream>>>(qadj, kadj, vt, out);
}

// Round 3
// 162.847 us; speedup vs baseline: 1.6655x; 1.0730x over previous
//
#include <hip/hip_runtime.h>
#include <hip/hip_bf16.h>
#include <math.h>

#define NB 4
#define NL 2048
#define NH 8
#define NE 64
#define ND 64
#define EPSF 1e-6f
#define CEXP 0.180336881f  // 0.125 * log2(e); scores L2-bounded in [-1,1] => fixed max 1.0

typedef __attribute__((ext_vector_type(8))) short bf16x8;
typedef __attribute__((ext_vector_type(4))) short s16x4;
typedef __attribute__((ext_vector_type(4))) float f32x4;

static __device__ __forceinline__ unsigned short bfbits(float x) {
  union { __hip_bfloat16 h; unsigned short u; } c;
  c.h = __float2bfloat16(x);
  return c.u;
}
static __device__ __forceinline__ float sgnsqrt(float x) {
  return x > 0.f ? sqrtf(x + EPSF) : (x < 0.f ? -sqrtf(-x + EPSF) : 0.f);
}

// ---------------- kernel 1: partial sums over L (no atomics, no memset) ---------
// grid (32 bh, 16 lp), 256 thr. pq/pk[bh][lp][64].
__global__ void sums_kernel(const float* __restrict__ q, const float* __restrict__ k,
                            float* __restrict__ pq, float* __restrict__ pk) {
  int bh = blockIdx.x, lp = blockIdx.y;
  int b = bh >> 3, h = bh & 7;
  int t = threadIdx.x;
  int eq = t & 15, lr = t >> 4;
  int wave = t >> 6, lane = t & 63;
  const float* qp = q + (((size_t)b * NL) * NH + h) * NE + eq * 4;
  const float* kp = k + (((size_t)b * NL) * NH + h) * NE + eq * 4;
  f32x4 aq = {0.f, 0.f, 0.f, 0.f}, ak = {0.f, 0.f, 0.f, 0.f};
#pragma unroll
  for (int i = 0; i < 8; ++i) {
    int l = lp * 128 + i * 16 + lr;
    size_t off = (size_t)l * NH * NE;
    aq += *(const f32x4*)(qp + off);
    ak += *(const f32x4*)(kp + off);
  }
#pragma unroll
  for (int c = 0; c < 4; ++c) {
    aq[c] += __shfl_xor(aq[c], 16, 64); aq[c] += __shfl_xor(aq[c], 32, 64);
    ak[c] += __shfl_xor(ak[c], 16, 64); ak[c] += __shfl_xor(ak[c], 32, 64);
  }
  __shared__ f32x4 sq[4][16], sk[4][16];
  if (lane < 16) { sq[wave][lane] = aq; sk[wave][lane] = ak; }
  __syncthreads();
  if (t < 16) {
    f32x4 s = sq[0][t] + sq[1][t] + sq[2][t] + sq[3][t];
    *(f32x4*)(pq + ((size_t)bh * 16 + lp) * 64 + t * 4) = s;
  } else if (t < 32) {
    int e = t - 16;
    f32x4 s = sk[0][e] + sk[1][e] + sk[2][e] + sk[3][e];
    *(f32x4*)(pk + ((size_t)bh * 16 + e < 0 ? 0 : ((size_t)bh * 16) + 0) * 0 + ((size_t)bh * 16 + lp) * 64 + e * 4) = s;
  }
}

// ---------------- kernel 2: fused adjust (blocks 0..1023) + vtrans (1024..2047) --
// adjust: 64 rows/block, float4 per lane, width-16 shuffle for L2 norm.
// vtrans: V [B,S,H,D] f32 -> VT [B,H,D,Sperm] bf16 with quad-interleaved columns:
//   storage col c (within 32-block): cq=c>>2, eg=cq>>1, hi=cq&1, s = hi*16+eg*4+(c&3)
__global__ void prep_kernel(const float* __restrict__ q, const float* __restrict__ k,
                            const float* __restrict__ v,
                            const float* __restrict__ pq, const float* __restrict__ pk,
                            const float* __restrict__ alpha,
                            __hip_bfloat16* __restrict__ qadj, __hip_bfloat16* __restrict__ kadj,
                            __hip_bfloat16* __restrict__ vt) {
  __shared__ float aqs[8][68], aks[8][68];
  __shared__ __hip_bfloat16 tile[64][68];
  int t = threadIdx.x;
  if (blockIdx.x < 1024) {
    // ---- adjust ----
    int rid0 = blockIdx.x * 64;
    int b = rid0 >> 14;
    {
      int h = t >> 5, j = t & 31;
      const float* pqp = pq + ((size_t)(b * 8 + h) * 16) * 64 + j * 2;
      const float* pkp = pk + ((size_t)(b * 8 + h) * 16) * 64 + j * 2;
      float s0 = 0.f, s1 = 0.f, u0 = 0.f, u1 = 0.f;
#pragma unroll
      for (int lp = 0; lp < 16; ++lp) {
        s0 += pqp[lp * 64]; s1 += pqp[lp * 64 + 1];
        u0 += pkp[lp * 64]; u1 += pkp[lp * 64 + 1];
      }
      float al = alpha[0];
      aqs[h][j * 2] = al * s0; aqs[h][j * 2 + 1] = al * s1;
      aks[h][j * 2] = al * u0; aks[h][j * 2 + 1] = al * u1;
    }
    __syncthreads();
    int eq = t & 15, lr = t >> 4;
#pragma unroll
    for (int p = 0; p < 4; ++p) {
      int rid = rid0 + p * 16 + lr;
      int h = rid & 7, l = (rid >> 3) & 2047;
      f32x4 q4 = *(const f32x4*)(q + (size_t)rid * 64 + eq * 4);
      f32x4 k4 = *(const f32x4*)(k + (size_t)rid * 64 + eq * 4);
      f32x4 xq = q4 + *(const f32x4*)&aks[h][eq * 4];  // q + alpha*k_sum
      f32x4 xk = k4 + *(const f32x4*)&aqs[h][eq * 4];  // k + alpha*q_sum
      float yq[4], yk[4];
      float nq = 0.f, nk = 0.f;
#pragma unroll
      for (int c = 0; c < 4; ++c) {
        yq[c] = sgnsqrt(xq[c]); nq += yq[c] * yq[c];
        yk[c] = sgnsqrt(xk[c]); nk += yk[c] * yk[c];
      }
#pragma unroll
      for (int m = 1; m < 16; m <<= 1) {
        nq += __shfl_xor(nq, m, 16);
        nk += __shfl_xor(nk, m, 16);
      }
      float iq = 1.f / (sqrtf(nq) + EPSF);
      float ik = 1.f / (sqrtf(nk) + EPSF);
      s16x4 uq, uk;
#pragma unroll
      for (int c = 0; c < 4; ++c) {
        uq[c] = (short)bfbits(yq[c] * iq);
        uk[c] = (short)bfbits(yk[c] * ik);
      }
      size_t ooff = ((size_t)(b * 8 + h) * 2048 + l) * 64 + eq * 4;
      *(s16x4*)((char*)qadj + ooff * 2) = uq;
      *(s16x4*)((char*)kadj + ooff * 2) = uk;
    }
  } else {
    // ---- vtrans (with column quad-interleave) ----
    int blk = blockIdx.x - 1024;
    int s0 = (blk & 31) * 64;
    int bh = blk >> 5;
    int b = bh >> 3, h = bh & 7;
    {
      int sl = t >> 2, dg = t & 3;
      const float* src = v + (((size_t)b * NL + s0 + sl) * NH + h) * ND + dg * 16;
#pragma unroll
      for (int i = 0; i < 4; ++i) {
        f32x4 f = *(const f32x4*)(src + i * 4);
        tile[sl][dg * 16 + i * 4 + 0] = __float2bfloat16(f[0]);
        tile[sl][dg * 16 + i * 4 + 1] = __float2bfloat16(f[1]);
        tile[sl][dg * 16 + i * 4 + 2] = __float2bfloat16(f[2]);
        tile[sl][dg * 16 + i * 4 + 3] = __float2bfloat16(f[3]);
      }
    }
    __syncthreads();
    {
      int d = t >> 2, sg = t & 3;
      __align__(16) __hip_bfloat16 tmp[16];
#pragma unroll
      for (int i = 0; i < 16; ++i) {
        int c = sg * 16 + i;
        int blk32 = c >> 5, cc = c & 31;
        int cq = cc >> 2, ege = cq >> 1, hi = cq & 1;
        int s_local = blk32 * 32 + hi * 16 + ege * 4 + (cc & 3);
        tmp[i] = tile[s_local][d];
      }
      __hip_bfloat16* dst = vt + ((size_t)bh * ND + d) * NL + s0 + sg * 16;
      *(bf16x8*)(dst) = *(const bf16x8*)&tmp[0];
      *(bf16x8*)(dst + 8) = *(const bf16x8*)&tmp[8];
    }
  }
}

// ---------------- kernel 3: causal flash attention ------------------------------
// 256 thr = 4 waves, 64 q-rows/tile, paired tiles (i, 31-i): uniform 33 steps.
// Swapped QK^T (P register-local), PV = V^T*P via k-slot permuted fragments.
// Triple-buffered K/V (3x16KB), depth-2 prefetch, counted vmcnt(4).
__global__ __launch_bounds__(256) void attn_kernel(const __hip_bfloat16* __restrict__ qadj,
                                                   const __hip_bfloat16* __restrict__ kadj,
                                                   const __hip_bfloat16* __restrict__ vt,
                                                   float* __restrict__ out) {
  __shared__ __align__(16) char lds[49152];
  int bh = blockIdx.x;      // fastest => same-bh blocks share an XCD (L2 locality)
  int pairid = blockIdx.y;  // 0..15
  int b = bh >> 3, h = bh & 7;
  int wave = threadIdx.x >> 6, lane = threadIdx.x & 63;
  int qr = lane & 15, eg = lane >> 4;
  const char* kgb = (const char*)(kadj + (size_t)bh * NL * NE);
  const char* vgb = (const char*)(vt + (size_t)bh * ND * NL);
  const char* qgb = (const char*)(qadj + (size_t)bh * NL * NE);

  auto STAGE = [&](int bufsel, int ck) {
    char* dstbase = lds + bufsel * 16384;
    int s0 = ck * 64;
#pragma unroll
    for (int c = 0; c < 4; ++c) {
      int T = (wave * 4 + c) * 1024 + lane * 16;
      const char* src;
      if (T < 8192) {  // K half: rows contiguous in global
        int S = T ^ (((T >> 7) & 7) << 4);
        src = kgb + (size_t)s0 * 128 + S;
      } else {         // V half: row d strided by NL
        int T2 = T - 8192;
        int S = T2 ^ (((T2 >> 7) & 7) << 4);
        int d = S >> 7, cc = S & 127;
        src = vgb + ((size_t)d * NL + s0) * 2 + cc;
      }
      __builtin_amdgcn_global_load_lds(
          (const __attribute__((address_space(1))) unsigned int*)src,
          (__attribute__((address_space(3))) unsigned int*)(dstbase + (wave * 4 + c) * 1024),
          16, 0, 0);
    }
  };

#pragma unroll 1
  for (int half = 0; half < 2; ++half) {
    int tile = half ? (31 - pairid) : pairid;
    int t0 = tile * 64;
    int nck = tile + 1;
    int qw0 = t0 + wave * 16;

    bf16x8 qf0 = *(const bf16x8*)(qgb + (size_t)(qw0 + qr) * 128 + eg * 16);
    bf16x8 qf1 = *(const bf16x8*)(qgb + (size_t)(qw0 + qr) * 128 + 64 + eg * 16);

    f32x4 acc[4];
#pragma unroll
    for (int dc = 0; dc < 4; ++dc) acc[dc] = (f32x4){0.f, 0.f, 0.f, 0.f};
    float srun = 0.f;

    if (half) {  // drain + fence before overwriting buffers still read by slow waves
      asm volatile("s_waitcnt vmcnt(0)" ::: "memory");
      __builtin_amdgcn_sched_barrier(0);
      __builtin_amdgcn_s_barrier();
    }
    STAGE(0, 0);
    if (nck > 1) STAGE(1, 1);

#pragma unroll 1
    for (int ck = 0; ck < nck; ++ck) {
      if (ck + 1 < nck) asm volatile("s_waitcnt vmcnt(4)" ::: "memory");
      else              asm volatile("s_waitcnt vmcnt(0)" ::: "memory");
      __builtin_amdgcn_sched_barrier(0);
      __builtin_amdgcn_s_barrier();
      __builtin_amdgcn_sched_barrier(0);
      if (ck + 2 < nck) STAGE((ck + 2) % 3, ck + 2);
      char* ldsK = lds + (ck % 3) * 16384;
      char* ldsV = ldsK + 8192;

      // ---- swapped QK^T: p[st][r] = P[s = ck*64+st*16+eg*4+r][q = qw0+qr] ----
      float p[4][4];
#pragma unroll
      for (int st = 0; st < 4; ++st) {
        f32x4 a = (f32x4){0.f, 0.f, 0.f, 0.f};
        int row = st * 16 + qr;
        int swz = (row & 7) << 4;
        bf16x8 k0 = *(const bf16x8*)(ldsK + ((row * 128 + eg * 16) ^ swz));
        bf16x8 k1 = *(const bf16x8*)(ldsK + ((row * 128 + 64 + eg * 16) ^ swz));
        a = __builtin_amdgcn_mfma_f32_16x16x32_bf16(k0, qf0, a, 0, 0, 0);
        a = __builtin_amdgcn_mfma_f32_16x16x32_bf16(k1, qf1, a, 0, 0, 0);
#pragma unroll
        for (int r = 0; r < 4; ++r) p[st][r] = a[r];
      }
      if (ck == nck - 1) {  // diagonal chunk: causal mask (strict s > q)
#pragma unroll
        for (int st = 0; st < 4; ++st)
#pragma unroll
          for (int r = 0; r < 4; ++r)
            if (t0 + st * 16 + eg * 4 + r > qw0 + qr) p[st][r] = -1e30f;
      }
      // ---- fixed-max softmax numerators; per-lane partial denominator ----
#pragma unroll
      for (int st = 0; st < 4; ++st)
#pragma unroll
        for (int r = 0; r < 4; ++r) p[st][r] = exp2f((p[st][r] - 1.0f) * CEXP);
      srun += ((p[0][0] + p[0][1] + p[0][2] + p[0][3]) + (p[1][0] + p[1][1] + p[1][2] + p[1][3])) +
              ((p[2][0] + p[2][1] + p[2][2] + p[2][3]) + (p[3][0] + p[3][1] + p[3][2] + p[3][3]));

      // ---- PV: O^T = V^T * P, B-frag straight from registers ----
#pragma unroll
      for (int pp = 0; pp < 2; ++pp) {
        bf16x8 pb;
#pragma unroll
        for (int j = 0; j < 4; ++j) {
          pb[j] = (short)bfbits(p[2 * pp][j]);
          pb[4 + j] = (short)bfbits(p[2 * pp + 1][j]);
        }
#pragma unroll
        for (int dc = 0; dc < 4; ++dc) {
          int d = dc * 16 + qr;
          bf16x8 vf = *(const bf16x8*)(ldsV + ((d * 128 + pp * 64 + eg * 16) ^ ((d & 7) << 4)));
          acc[dc] = __builtin_amdgcn_mfma_f32_16x16x32_bf16(vf, pb, acc[dc], 0, 0, 0);
        }
      }
    }

    // ---- epilogue: finish denominator over eg groups, normalize, store ----
    srun += __shfl_xor(srun, 16, 64);
    srun += __shfl_xor(srun, 32, 64);
    float inv = 1.f / srun;
    int l = qw0 + qr;
    float* orow = out + (((size_t)b * NL + l) * NH + h) * ND;
#pragma unroll
    for (int dc = 0; dc < 4; ++dc) *(f32x4*)(orow + dc * 16 + eg * 4) = acc[dc] * inv;
  }
}

extern "C" void kernel_launch(void* const* d_in, const int* in_sizes, int n_in,
                              void* d_out, int out_size, void* d_ws, size_t ws_size,
                              hipStream_t stream) {
  const float* q = (const float*)d_in[0];
  const float* k = (const float*)d_in[1];
  const float* v = (const float*)d_in[2];
  // d_in[3] = attn_mask: deterministic triu(k=1) causal mask — applied analytically
  const float* alpha = (const float*)d_in[4];
  float* out = (float*)d_out;
  char* ws = (char*)d_ws;

  __hip_bfloat16* qadj = (__hip_bfloat16*)(ws);                 // 8 MiB [B,H,L,E]
  __hip_bfloat16* kadj = (__hip_bfloat16*)(ws + 8388608);       // 8 MiB [B,H,L,E]
  __hip_bfloat16* vt   = (__hip_bfloat16*)(ws + 16777216);      // 8 MiB [B,H,D,Sperm]
  float* pq = (float*)(ws + 25165824);                          // 128 KiB partials
  float* pk = (float*)(ws + 25165824 + 131072);                 // 128 KiB partials

  sums_kernel<<<dim3(32, 16), 256, 0, stream>>>(q, k, pq, pk);
  prep_kernel<<<dim3(2048), 256, 0, stream>>>(q, k, v, pq, pk, alpha, qadj, kadj, vt);
  attn_kernel<<<dim3(32, 16), 256, 0, stream>>>(qadj, kadj, vt, out);
}

// Round 4
// 151.693 us; speedup vs baseline: 1.7880x; 1.0735x over previous
//
#include <hip/hip_runtime.h>
#include <hip/hip_bf16.h>
#include <math.h>

#define NB 4
#define NL 2048
#define NH 8
#define NE 64
#define ND 64
#define EPSF 1e-6f
#define CEXP 0.180336881f  // 0.125 * log2(e); scores L2-bounded in [-1,1] => fixed max 1.0

typedef __attribute__((ext_vector_type(8))) short bf16x8;
typedef __attribute__((ext_vector_type(4))) short s16x4;
typedef __attribute__((ext_vector_type(4))) float f32x4;

static __device__ __forceinline__ unsigned short bfbits(float x) {
  union { __hip_bfloat16 h; unsigned short u; } c;
  c.h = __float2bfloat16(x);
  return c.u;
}
static __device__ __forceinline__ float sgnsqrt(float x) {
  return x > 0.f ? sqrtf(x + EPSF) : (x < 0.f ? -sqrtf(-x + EPSF) : 0.f);
}

// ---------------- kernel 1: partial sums over L (no atomics, no memset) ---------
__global__ void sums_kernel(const float* __restrict__ q, const float* __restrict__ k,
                            float* __restrict__ pq, float* __restrict__ pk) {
  int bh = blockIdx.x, lp = blockIdx.y;
  int b = bh >> 3, h = bh & 7;
  int t = threadIdx.x;
  int eq = t & 15, lr = t >> 4;
  int wave = t >> 6, lane = t & 63;
  const float* qp = q + (((size_t)b * NL) * NH + h) * NE + eq * 4;
  const float* kp = k + (((size_t)b * NL) * NH + h) * NE + eq * 4;
  f32x4 aq = {0.f, 0.f, 0.f, 0.f}, ak = {0.f, 0.f, 0.f, 0.f};
#pragma unroll
  for (int i = 0; i < 8; ++i) {
    int l = lp * 128 + i * 16 + lr;
    size_t off = (size_t)l * NH * NE;
    aq += *(const f32x4*)(qp + off);
    ak += *(const f32x4*)(kp + off);
  }
#pragma unroll
  for (int c = 0; c < 4; ++c) {
    aq[c] += __shfl_xor(aq[c], 16, 64); aq[c] += __shfl_xor(aq[c], 32, 64);
    ak[c] += __shfl_xor(ak[c], 16, 64); ak[c] += __shfl_xor(ak[c], 32, 64);
  }
  __shared__ f32x4 sq[4][16], sk[4][16];
  if (lane < 16) { sq[wave][lane] = aq; sk[wave][lane] = ak; }
  __syncthreads();
  if (t < 16) {
    f32x4 s = sq[0][t] + sq[1][t] + sq[2][t] + sq[3][t];
    *(f32x4*)(pq + ((size_t)bh * 16 + lp) * 64 + t * 4) = s;
  } else if (t < 32) {
    int e = t - 16;
    f32x4 s = sk[0][e] + sk[1][e] + sk[2][e] + sk[3][e];
    *(f32x4*)(pk + ((size_t)bh * 16 + lp) * 64 + e * 4) = s;
  }
}

// ---------------- kernel 2: fused adjust (blocks 0..1023) + vtrans (1024..2047) --
// vtrans V [B,S,H,D] f32 -> VT [B,H,D,Sperm] bf16, column quad-interleave so PV's
// A-fragment reads are contiguous: storage col c -> s = blk32*32+hi*16+ege*4+(c&3).
__global__ void prep_kernel(const float* __restrict__ q, const float* __restrict__ k,
                            const float* __restrict__ v,
                            const float* __restrict__ pq, const float* __restrict__ pk,
                            const float* __restrict__ alpha,
                            __hip_bfloat16* __restrict__ qadj, __hip_bfloat16* __restrict__ kadj,
                            __hip_bfloat16* __restrict__ vt) {
  __shared__ float aqs[8][68], aks[8][68];
  __shared__ __hip_bfloat16 tile[64][68];
  int t = threadIdx.x;
  if (blockIdx.x < 1024) {
    // ---- adjust ----
    int rid0 = blockIdx.x * 64;
    int b = rid0 >> 14;
    {
      int h = t >> 5, j = t & 31;
      const float* pqp = pq + ((size_t)(b * 8 + h) * 16) * 64 + j * 2;
      const float* pkp = pk + ((size_t)(b * 8 + h) * 16) * 64 + j * 2;
      float s0 = 0.f, s1 = 0.f, u0 = 0.f, u1 = 0.f;
#pragma unroll
      for (int lp = 0; lp < 16; ++lp) {
        s0 += pqp[lp * 64]; s1 += pqp[lp * 64 + 1];
        u0 += pkp[lp * 64]; u1 += pkp[lp * 64 + 1];
      }
      float al = alpha[0];
      aqs[h][j * 2] = al * s0; aqs[h][j * 2 + 1] = al * s1;
      aks[h][j * 2] = al * u0; aks[h][j * 2 + 1] = al * u1;
    }
    __syncthreads();
    int eq = t & 15, lr = t >> 4;
#pragma unroll
    for (int p = 0; p < 4; ++p) {
      int rid = rid0 + p * 16 + lr;
      int h = rid & 7, l = (rid >> 3) & 2047;
      f32x4 q4 = *(const f32x4*)(q + (size_t)rid * 64 + eq * 4);
      f32x4 k4 = *(const f32x4*)(k + (size_t)rid * 64 + eq * 4);
      f32x4 xq = q4 + *(const f32x4*)&aks[h][eq * 4];  // q + alpha*k_sum
      f32x4 xk = k4 + *(const f32x4*)&aqs[h][eq * 4];  // k + alpha*q_sum
      float yq[4], yk[4];
      float nq = 0.f, nk = 0.f;
#pragma unroll
      for (int c = 0; c < 4; ++c) {
        yq[c] = sgnsqrt(xq[c]); nq += yq[c] * yq[c];
        yk[c] = sgnsqrt(xk[c]); nk += yk[c] * yk[c];
      }
#pragma unroll
      for (int m = 1; m < 16; m <<= 1) {
        nq += __shfl_xor(nq, m, 16);
        nk += __shfl_xor(nk, m, 16);
      }
      float iq = 1.f / (sqrtf(nq) + EPSF);
      float ik = 1.f / (sqrtf(nk) + EPSF);
      s16x4 uq, uk;
#pragma unroll
      for (int c = 0; c < 4; ++c) {
        uq[c] = (short)bfbits(yq[c] * iq);
        uk[c] = (short)bfbits(yk[c] * ik);
      }
      size_t ooff = ((size_t)(b * 8 + h) * 2048 + l) * 64 + eq * 4;
      *(s16x4*)((char*)qadj + ooff * 2) = uq;
      *(s16x4*)((char*)kadj + ooff * 2) = uk;
    }
  } else {
    // ---- vtrans (with column quad-interleave) ----
    int blk = blockIdx.x - 1024;
    int s0 = (blk & 31) * 64;
    int bh = blk >> 5;
    int b = bh >> 3, h = bh & 7;
    {
      int sl = t >> 2, dg = t & 3;
      const float* src = v + (((size_t)b * NL + s0 + sl) * NH + h) * ND + dg * 16;
#pragma unroll
      for (int i = 0; i < 4; ++i) {
        f32x4 f = *(const f32x4*)(src + i * 4);
        tile[sl][dg * 16 + i * 4 + 0] = __float2bfloat16(f[0]);
        tile[sl][dg * 16 + i * 4 + 1] = __float2bfloat16(f[1]);
        tile[sl][dg * 16 + i * 4 + 2] = __float2bfloat16(f[2]);
        tile[sl][dg * 16 + i * 4 + 3] = __float2bfloat16(f[3]);
      }
    }
    __syncthreads();
    {
      int d = t >> 2, sg = t & 3;
      __align__(16) __hip_bfloat16 tmp[16];
#pragma unroll
      for (int i = 0; i < 16; ++i) {
        int c = sg * 16 + i;
        int blk32 = c >> 5, cc = c & 31;
        int cq = cc >> 2, ege = cq >> 1, hi = cq & 1;
        int s_local = blk32 * 32 + hi * 16 + ege * 4 + (cc & 3);
        tmp[i] = tile[s_local][d];
      }
      __hip_bfloat16* dst = vt + ((size_t)bh * ND + d) * NL + s0 + sg * 16;
      *(bf16x8*)(dst) = *(const bf16x8*)&tmp[0];
      *(bf16x8*)(dst + 8) = *(const bf16x8*)&tmp[8];
    }
  }
}

// ---------------- kernel 3: causal flash attention ------------------------------
// 256 thr = 4 waves: wave = (qhalf, shalf). 32 q-rows/block, one tile per block,
// chunks of 64 s; each wave: 16 q x 32 s. Grid 32 bh x 64 tiles (big-first).
// LDS 32KB double-buffer -> 5 blocks/CU = 20 waves/CU. Epilogue merges s-halves.
__global__ __launch_bounds__(256, 5) void attn_kernel(const __hip_bfloat16* __restrict__ qadj,
                                                      const __hip_bfloat16* __restrict__ kadj,
                                                      const __hip_bfloat16* __restrict__ vt,
                                                      float* __restrict__ out) {
  __shared__ __align__(16) char lds[32768];
  int bh = blockIdx.x;              // fastest => same-bh blocks cluster on an XCD
  int tile = 63 - (int)blockIdx.y;  // big tiles dispatch first
  int b = bh >> 3, h = bh & 7;
  int wave = threadIdx.x >> 6, lane = threadIdx.x & 63;
  int qr = lane & 15, eg = lane >> 4;
  int qhalf = wave >> 1, shalf = wave & 1;
  int t0 = tile * 32;
  int nck = (tile >> 1) + 1;
  int qw0 = t0 + qhalf * 16;
  const char* kgb = (const char*)(kadj + (size_t)bh * NL * NE);
  const char* vgb = (const char*)(vt + (size_t)bh * ND * NL);
  const char* qgb = (const char*)(qadj + (size_t)bh * NL * NE);

  // ---- hoisted LDS fragment offsets (loop-invariant) ----
  int koff[2][2], voff[4];
#pragma unroll
  for (int st2 = 0; st2 < 2; ++st2) {
    int row = shalf * 32 + st2 * 16 + qr;
    int swz = (row & 7) << 4;
    koff[st2][0] = (row * 128 + eg * 16) ^ swz;
    koff[st2][1] = (row * 128 + 64 + eg * 16) ^ swz;
  }
#pragma unroll
  for (int dc = 0; dc < 4; ++dc) {
    int d = dc * 16 + qr;
    voff[dc] = 8192 + ((d * 128 + shalf * 64 + eg * 16) ^ ((d & 7) << 4));
  }
  // ---- hoisted staging source/dest offsets: waves 0-1 stage K, 2-3 stage V ----
  int src_off[4], dst_off[4];
#pragma unroll
  for (int c = 0; c < 4; ++c) {
    dst_off[c] = (wave * 4 + c) * 1024;
    if (wave < 2) {
      int T = (wave * 4 + c) * 1024 + lane * 16;
      src_off[c] = T ^ (((T >> 7) & 7) << 4);
    } else {
      int T2 = ((wave - 2) * 4 + c) * 1024 + lane * 16;
      int S = T2 ^ (((T2 >> 7) & 7) << 4);
      src_off[c] = (S >> 7) * (NL * 2) + (S & 127);
    }
  }
  const char* sgb = (wave < 2) ? kgb : vgb;
  int smul = (wave < 2) ? 8192 : 128;  // bytes per 64-s chunk step in global

  auto STAGE = [&](int bufsel, int ck) {
    const char* sb = sgb + (size_t)ck * smul;
    char* db = lds + bufsel * 16384;
#pragma unroll
    for (int c = 0; c < 4; ++c)
      __builtin_amdgcn_global_load_lds(
          (const __attribute__((address_space(1))) unsigned int*)(sb + src_off[c]),
          (__attribute__((address_space(3))) unsigned int*)(db + dst_off[c]),
          16, 0, 0);
  };

  bf16x8 qf0 = *(const bf16x8*)(qgb + (size_t)(qw0 + qr) * 128 + eg * 16);
  bf16x8 qf1 = *(const bf16x8*)(qgb + (size_t)(qw0 + qr) * 128 + 64 + eg * 16);

  f32x4 acc[4];
#pragma unroll
  for (int dc = 0; dc < 4; ++dc) acc[dc] = (f32x4){0.f, 0.f, 0.f, 0.f};
  float srun = 0.f;

  STAGE(0, 0);
#pragma unroll 1
  for (int ck = 0; ck < nck; ++ck) {
    asm volatile("s_waitcnt vmcnt(0)" ::: "memory");
    __builtin_amdgcn_sched_barrier(0);
    __builtin_amdgcn_s_barrier();
    __builtin_amdgcn_sched_barrier(0);
    if (ck + 1 < nck) STAGE((ck + 1) & 1, ck + 1);  // flies under this chunk's compute
    char* base = lds + (ck & 1) * 16384;

    // ---- swapped QK^T: p[st2][r] = P[s][q], s = ck*64+shalf*32+st2*16+eg*4+r ----
    float p[2][4];
#pragma unroll
    for (int st2 = 0; st2 < 2; ++st2) {
      f32x4 a = (f32x4){0.f, 0.f, 0.f, 0.f};
      bf16x8 k0 = *(const bf16x8*)(base + koff[st2][0]);
      bf16x8 k1 = *(const bf16x8*)(base + koff[st2][1]);
      a = __builtin_amdgcn_mfma_f32_16x16x32_bf16(k0, qf0, a, 0, 0, 0);
      a = __builtin_amdgcn_mfma_f32_16x16x32_bf16(k1, qf1, a, 0, 0, 0);
#pragma unroll
      for (int r = 0; r < 4; ++r) p[st2][r] = a[r];
    }
    if (ck == nck - 1) {  // diagonal chunk: strict causal mask s > q
      int sbase = ck * 64 + shalf * 32 + eg * 4;
      int qg = qw0 + qr;
#pragma unroll
      for (int st2 = 0; st2 < 2; ++st2)
#pragma unroll
        for (int r = 0; r < 4; ++r)
          if (sbase + st2 * 16 + r > qg) p[st2][r] = -1e30f;
    }
    // ---- fixed-max softmax numerators; per-lane partial denominator ----
#pragma unroll
    for (int st2 = 0; st2 < 2; ++st2)
#pragma unroll
      for (int r = 0; r < 4; ++r) p[st2][r] = exp2f((p[st2][r] - 1.0f) * CEXP);
    srun += ((p[0][0] + p[0][1]) + (p[0][2] + p[0][3])) +
            ((p[1][0] + p[1][1]) + (p[1][2] + p[1][3]));

    // ---- PV: O^T = V^T * P, B-fragment direct from registers ----
    bf16x8 pb;
#pragma unroll
    for (int j = 0; j < 4; ++j) {
      pb[j] = (short)bfbits(p[0][j]);
      pb[4 + j] = (short)bfbits(p[1][j]);
    }
#pragma unroll
    for (int dc = 0; dc < 4; ++dc) {
      bf16x8 vf = *(const bf16x8*)(base + voff[dc]);
      acc[dc] = __builtin_amdgcn_mfma_f32_16x16x32_bf16(vf, pb, acc[dc], 0, 0, 0);
    }
  }

  // ---- epilogue: reduce srun over eg, merge s-halves via LDS, store ----
  srun += __shfl_xor(srun, 16, 64);
  srun += __shfl_xor(srun, 32, 64);
  __syncthreads();  // all K/V reads drained; buffers reusable as merge area
  if (shalf == 1) {
    float* m = (float*)(lds + qhalf * 4352 + lane * 68);
#pragma unroll
    for (int dc = 0; dc < 4; ++dc)
#pragma unroll
      for (int r = 0; r < 4; ++r) m[dc * 4 + r] = acc[dc][r];
    m[16] = srun;
  }
  __syncthreads();
  if (shalf == 0) {
    const float* m = (const float*)(lds + qhalf * 4352 + lane * 68);
#pragma unroll
    for (int dc = 0; dc < 4; ++dc)
#pragma unroll
      for (int r = 0; r < 4; ++r) acc[dc][r] += m[dc * 4 + r];
    float inv = 1.f / (srun + m[16]);
    int l = qw0 + qr;
    float* orow = out + (((size_t)b * NL + l) * NH + h) * ND;
#pragma unroll
    for (int dc = 0; dc < 4; ++dc) *(f32x4*)(orow + dc * 16 + eg * 4) = acc[dc] * inv;
  }
}

extern "C" void kernel_launch(void* const* d_in, const int* in_sizes, int n_in,
                              void* d_out, int out_size, void* d_ws, size_t ws_size,
                              hipStream_t stream) {
  const float* q = (const float*)d_in[0];
  const float* k = (const float*)d_in[1];
  const float* v = (const float*)d_in[2];
  // d_in[3] = attn_mask: deterministic triu(k=1) causal mask — applied analytically
  const float* alpha = (const float*)d_in[4];
  float* out = (float*)d_out;
  char* ws = (char*)d_ws;

  __hip_bfloat16* qadj = (__hip_bfloat16*)(ws);                 // 8 MiB [B,H,L,E]
  __hip_bfloat16* kadj = (__hip_bfloat16*)(ws + 8388608);       // 8 MiB [B,H,L,E]
  __hip_bfloat16* vt   = (__hip_bfloat16*)(ws + 16777216);      // 8 MiB [B,H,D,Sperm]
  float* pq = (float*)(ws + 25165824);                          // 128 KiB partials
  float* pk = (float*)(ws + 25165824 + 131072);                 // 128 KiB partials

  sums_kernel<<<dim3(32, 16), 256, 0, stream>>>(q, k, pq, pk);
  prep_kernel<<<dim3(2048), 256, 0, stream>>>(q, k, v, pq, pk, alpha, qadj, kadj, vt);
  attn_kernel<<<dim3(32, 64), 256, 0, stream>>>(qadj, kadj, vt, out);
}